// Round 12
// baseline (280.796 us; speedup 1.0000x reference)
//
#include <hip/hip_runtime.h>
#include <stdint.h>

typedef unsigned short u16;
typedef unsigned int u32;
typedef __bf16 b16x8 __attribute__((ext_vector_type(8)));
typedef float f32x4 __attribute__((ext_vector_type(4)));

#define B_ 8
#define S_ 1024
#define H_ 16
#define HD_ 64
#define D_ 1024
#define M_ 8192

__device__ __forceinline__ u16 f2bf(float f) {
  u32 u = __float_as_uint(f);
  return (u16)((u + 0x7fffu + ((u >> 16) & 1u)) >> 16);
}
__device__ __forceinline__ u16 bfbits(float f) {
  union {
    __bf16 b;
    u16 u;
  } c;
  c.b = (__bf16)f;  // native V_CVT (RNE)
  return c.u;
}

__device__ __forceinline__ f32x4 mfma16(b16x8 a, b16x8 b, f32x4 c) {
  return __builtin_amdgcn_mfma_f32_16x16x32_bf16(a, b, c, 0, 0, 0);
}

// async global->LDS, 16B per lane. LDS dest = wave-uniform base + lane*16.
__device__ __forceinline__ void cp16(const u16* g, u16* l) {
  __builtin_amdgcn_global_load_lds(
      (const __attribute__((address_space(1))) u32*)(g),
      (__attribute__((address_space(3))) u32*)(l), 16, 0, 0);
}

// ---------------------------------------------------------------------------
// Weight convert+transpose: WT[n][k] = bf16(W[k][n]), W f32 1024x1024.
// wtq/wtk/wtv land contiguous in ws -> fused B matrix [3072][1024] for QKV.
// ---------------------------------------------------------------------------
__global__ __launch_bounds__(1024) void wconv_kernel(
    const float* __restrict__ w0, const float* __restrict__ w1,
    const float* __restrict__ w2, const float* __restrict__ w3,
    u16* __restrict__ t0, u16* __restrict__ t1, u16* __restrict__ t2,
    u16* __restrict__ t3) {
  __shared__ float tile[32][33];
  const int z = blockIdx.z;
  const float* src = (z == 0) ? w0 : (z == 1) ? w1 : (z == 2) ? w2 : w3;
  u16* dst = (z == 0) ? t0 : (z == 1) ? t1 : (z == 2) ? t2 : t3;
  const int tx = threadIdx.x, ty = threadIdx.y;
  const int x0 = blockIdx.x * 32, y0 = blockIdx.y * 32;
  tile[ty][tx] = src[(size_t)(y0 + ty) * D_ + x0 + tx];
  __syncthreads();
  dst[(size_t)(x0 + ty) * D_ + y0 + tx] = f2bf(tile[tx][ty]);
}

// ---------------------------------------------------------------------------
// x convert: f32 -> bf16, 8M elements, 4/thread
// ---------------------------------------------------------------------------
__global__ __launch_bounds__(256) void xconv_kernel(const float* __restrict__ x,
                                                    u16* __restrict__ xb) {
  const size_t i = ((size_t)blockIdx.x * 256 + threadIdx.x) * 4;
  const float4 v = *(const float4*)(x + i);
  u16 o[4] = {f2bf(v.x), f2bf(v.y), f2bf(v.z), f2bf(v.w)};
  uint2 pack;
  pack.x = ((u32)o[1] << 16) | o[0];
  pack.y = ((u32)o[3] << 16) | o[2];
  *(uint2*)(xb + i) = pack;
}

// ---------------------------------------------------------------------------
// 128x128 GEMM mainloop, BK=64, 256 threads (4 waves, 2Mx2N, wave 64x64),
// double-buffered LDS 2x32KB = 64KB -> 2 BLOCKS/CU CO-RESIDENT.
// ROUND-12 RATIONALE: rounds 7/9/11 falsified barrier-placement, read-clump,
// and read-volume theories at 1 block/CU (all ~flat at ~670 TF). The
// documented m97 mechanism (912 TF, same HW) is the SAME simple loop with
// 2-3 co-resident blocks: when one block sits in vmcnt/barrier drain, the
// other block's waves fill the SIMDs. 144KB LDS forbade that; 64KB restores
// it. Staging geometry identical to the verified round-0 kernel (32-row
// pieces, XOR chunk swizzle, measured 0 conflicts); counted-vmcnt discipline
// identical to verified rounds 5-11 (depth-1 here: 8 loads/stage, vmcnt(8)
// mid-loop, never 0; mid-tile lgkmcnt(0)+barrier = WAR chain for restage).
// acc[4][4]=64 + 16 frags + addr ~= 150 VGPR -- no spill risk (r4/r10
// lesson: acc=128 @512thr spills).
// ---------------------------------------------------------------------------
#define BUF128_ 16384  // u16 per buffer: A 128x64 (8192) + B 128x64 (8192)

__device__ __forceinline__ void gemm128_mainloop(
    const u16* __restrict__ A, const u16* __restrict__ BT, int K, int m0,
    int n0, u16* lds, f32x4 (&acc)[4][4]) {
  const int t = threadIdx.x;
  const int lane = t & 63;
  const int l15 = lane & 15;
  const int q4 = lane >> 4;
  const int w = t >> 6;            // 0..3
  const int mwave = (w >> 1) * 64; // 2M x 2N wave grid, 64x64 each
  const int nwave = (w & 1) * 64;

  const f32x4 zero = {0.f, 0.f, 0.f, 0.f};
#pragma unroll
  for (int mt = 0; mt < 4; ++mt)
#pragma unroll
    for (int nt = 0; nt < 4; ++nt) acc[mt][nt] = zero;

  const int rbase = t >> 3;                      // 0..31
  const int scol = ((t & 7) ^ (rbase & 7)) * 8;  // pre-swizzled global col
  const u16* Ag = A + (size_t)(m0 + rbase) * K + scol;
  const u16* Bg = BT + (size_t)(n0 + rbase) * K + scol;
  const int sx = l15 & 7;

  // one stage = 8 cp16/thread (4x A 32-row pieces + 4x B)
  auto STAGE = [&](int kt, int bufi) {
    u16* Ab = lds + bufi * BUF128_;
    u16* Bb = Ab + 8192;
    const int k0 = kt * 64;
#pragma unroll
    for (int c = 0; c < 4; ++c)
      cp16(Ag + (size_t)(c * 32) * K + k0, Ab + c * 2048 + t * 8);
#pragma unroll
    for (int c = 0; c < 4; ++c)
      cp16(Bg + (size_t)(c * 32) * K + k0, Bb + c * 2048 + t * 8);
  };

  const int NT = K / 64;  // 16
  STAGE(0, 0);

  int cur = 0;
  for (int kt = 0; kt < NT; ++kt) {
    if (kt + 1 < NT) STAGE(kt + 1, cur ^ 1);  // issue BEFORE the wait
    // readiness of buf[cur]: retire only the oldest 8 (counted vmcnt)
    if (kt + 1 < NT)
      asm volatile("s_waitcnt vmcnt(8)" ::: "memory");
    else
      asm volatile("s_waitcnt vmcnt(0)" ::: "memory");
    asm volatile("s_barrier" ::: "memory");

    const u16* Ab = lds + cur * BUF128_;
    const u16* Bb = Ab + 8192;

    // all 16 fragment reads for both kk halves, back-to-back (kk0 first)
    b16x8 af[4][2], bf2[4][2];
#pragma unroll
    for (int kk = 0; kk < 2; ++kk) {
      const int cc = ((kk * 4 + q4) ^ sx) * 8;
#pragma unroll
      for (int mt = 0; mt < 4; ++mt)
        af[mt][kk] = *(const b16x8*)(Ab + (mwave + mt * 16 + l15) * 64 + cc);
#pragma unroll
      for (int nt = 0; nt < 4; ++nt)
        bf2[nt][kk] = *(const b16x8*)(Bb + (nwave + nt * 16 + l15) * 64 + cc);
    }
    __builtin_amdgcn_sched_barrier(0);

    // kk0 MFMA (compiler inserts counted lgkm waits)
    __builtin_amdgcn_s_setprio(1);
#pragma unroll
    for (int mt = 0; mt < 4; ++mt)
#pragma unroll
      for (int nt = 0; nt < 4; ++nt)
        acc[mt][nt] = mfma16(af[mt][0], bf2[nt][0], acc[mt][nt]);
    __builtin_amdgcn_s_setprio(0);

    // all waves' reads of buf[cur] complete before anyone can restage it
    asm volatile("s_waitcnt lgkmcnt(0)" ::: "memory");
    asm volatile("s_barrier" ::: "memory");

    __builtin_amdgcn_s_setprio(1);
#pragma unroll
    for (int mt = 0; mt < 4; ++mt)
#pragma unroll
      for (int nt = 0; nt < 4; ++nt)
        acc[mt][nt] = mfma16(af[mt][1], bf2[nt][1], acc[mt][nt]);
    __builtin_amdgcn_s_setprio(0);

    cur ^= 1;
  }
}

// ---------------------------------------------------------------------------
// Fused QKV projection: one GEMM M=8192 x N=3072 (B = [wtq;wtk;wtv]).
// 128x128 tiles: grid 1536 = 64by x 24bx, 2 blocks/CU -> 3 rounds.
// L2 swizzle: XCD x owns by in {8x..8x+7} (A band 2MB hot), sweeps bx
// (resident B ~2MB) -> ~4MB/XCD working set.
// z=0 -> Q [B,H,S,HD], z=1 -> K [B,H,S,HD], z=2 -> V^T [B,H,HD,S]
// ---------------------------------------------------------------------------
__global__ __launch_bounds__(256, 2) void qkv_gemm_kernel(
    const u16* __restrict__ xb, const u16* __restrict__ wt3,
    const float* __restrict__ bq, const float* __restrict__ bk,
    const float* __restrict__ bv, u16* __restrict__ Q, u16* __restrict__ Kb,
    u16* __restrict__ VT) {
  __shared__ __align__(16) u16 lds[2 * BUF128_];  // 64 KB
  const int wg = blockIdx.x;
  const int xcd = wg & 7;
  const int s = wg >> 3;             // 0..191
  const int by = xcd * 8 + (s & 7);  // 0..63: 8 A-panels pinned per XCD
  const int bx = s >> 3;             // 0..23: B streams
  const int m0 = by * 128;
  const int n0 = bx * 128;  // fused col base 0..2944

  f32x4 acc[4][4];
  gemm128_mainloop(xb, wt3, D_, m0, n0, lds, acc);

  const int t = threadIdx.x;
  const int lane = t & 63, w = t >> 6;
  const int l15 = lane & 15, q4 = lane >> 4;
  const int mwave = (w >> 1) * 64, nwave = (w & 1) * 64;

  const int z = n0 >> 10;  // uniform per block
  u16* out = (z == 0) ? Q : (z == 1) ? Kb : VT;
  const float* bias = (z == 0) ? bq : (z == 1) ? bk : bv;

  for (int nt = 0; nt < 4; ++nt) {
    const int nf = n0 + nwave + nt * 16 + l15;  // fused col
    const int n1 = nf & 1023;                   // col within matrix
    const float bias_v = bias[n1];
    const int h = n1 >> 6, hd = n1 & 63;
    for (int mt = 0; mt < 4; ++mt) {
      for (int r = 0; r < 4; ++r) {
        const int m = m0 + mwave + mt * 16 + q4 * 4 + r;
        const int b = m >> 10, ss = m & 1023;
        const float v = acc[mt][nt][r] + bias_v;
        size_t idx;
        if (z < 2)
          idx = (((size_t)(b * H_ + h)) * S_ + ss) * HD_ + hd;
        else
          idx = (((size_t)(b * H_ + h)) * HD_ + hd) * S_ + ss;
        out[idx] = f2bf(v);
      }
    }
  }
}

// ---------------------------------------------------------------------------
// Flash attention, fixed-max softmax, transposed-score formulation.
// QBLK=128 (512 threads, 8 waves), verified round-6. Unchanged.
// ---------------------------------------------------------------------------
#define PAD_ 68   // K/V row stride (measured conflict-free)
#define QPAD_ 72  // Q/P row stride (144B = 16B-aligned for b128)
__global__ __launch_bounds__(512) void attn_kernel(
    const u16* __restrict__ Q, const u16* __restrict__ Kb,
    const u16* __restrict__ VT, const int* __restrict__ mask,
    u16* __restrict__ ctx) {
  __shared__ __align__(16) u16 QPlds[128 * QPAD_];  // Q tile, then P buffers
  __shared__ __align__(16) u16 Klds[64 * PAD_];
  __shared__ __align__(16) u16 Vlds[64 * PAD_];
  __shared__ __align__(16) float Mlds[1024];  // -14427 * mask[key]

  const int t = threadIdx.x;
  const int lane = t & 63, w = t >> 6;  // w 0..7
  const int l15 = lane & 15, q4 = lane >> 4;
  const int id = blockIdx.x;
  const int bh = id & 127;  // XCD = id%8 = bh%8 -> q-tiles of a bh co-locate
  const int b = bh >> 4, h = bh & 15;
  const int q0 = (id >> 7) * 128;  // 8 q-tiles of 128 rows

  const u16* Qbh = Q + (size_t)bh * S_ * HD_;
  const u16* Kbh = Kb + (size_t)bh * S_ * HD_;
  const u16* Vbh = VT + (size_t)bh * S_ * HD_;  // [HD][S]
  const int* maskb = mask + b * S_;

  const int srow = t >> 3, scol = (t & 7) * 8;  // srow 0..63
  {  // stage Q tile [128][64] + mask into LDS
    b16x8 q0v = *(const b16x8*)(Qbh + (size_t)(q0 + srow) * HD_ + scol);
    b16x8 q1v = *(const b16x8*)(Qbh + (size_t)(q0 + srow + 64) * HD_ + scol);
    const int2 mv = *(const int2*)(maskb + t * 2);
    *(b16x8*)(QPlds + srow * QPAD_ + scol) = q0v;
    *(b16x8*)(QPlds + (srow + 64) * QPAD_ + scol) = q1v;
    float2 mf;
    mf.x = -14427.0f * (float)mv.x;
    mf.y = -14427.0f * (float)mv.y;
    *(float2*)(Mlds + t * 2) = mf;
  }
  __syncthreads();
  // Q B-frags (lane holds Q[q=l15][d=q4*8+j]), wave-private rows
  b16x8 aq[2];
  aq[0] = *(const b16x8*)(QPlds + (w * 16 + l15) * QPAD_ + q4 * 8);
  aq[1] = *(const b16x8*)(QPlds + (w * 16 + l15) * QPAD_ + 32 + q4 * 8);

  const f32x4 zero = {0.f, 0.f, 0.f, 0.f};
  f32x4 acc[4];  // O^T tiles: acc[nt] row d=nt*16+q4*4+r, col q=l15
  for (int nt = 0; nt < 4; ++nt) acc[nt] = zero;
  float lsum = 0.f;                  // partial row-sum for q=l15
  u16* Pw = QPlds + w * 16 * QPAD_;  // wave-private P: [q(16)][key(64)]
  const float c1 = 0.18033688f;      // 0.125 * log2(e)

  // prologue: K/V registers for j=0 (one row each with 512 threads)
  b16x8 kv0 = *(const b16x8*)(Kbh + (size_t)srow * HD_ + scol);
  b16x8 vv0 = *(const b16x8*)(Vbh + (size_t)srow * S_ + scol);

  for (int j = 0; j < 16; ++j) {
    const int key0 = j * 64;
    __syncthreads();  // (A) prior iteration's K/V LDS reads complete
    *(b16x8*)(Klds + srow * PAD_ + scol) = kv0;
    *(b16x8*)(Vlds + srow * PAD_ + scol) = vv0;
    __syncthreads();  // (B) staging visible

    if (j < 15) {  // prefetch next tile's K/V during compute
      const int kn = key0 + 64;
      kv0 = *(const b16x8*)(Kbh + (size_t)(kn + srow) * HD_ + scol);
      vv0 = *(const b16x8*)(Vbh + (size_t)srow * S_ + kn + scol);
    }

    // S^T = K·Q^T: sf[nt] rows key=nt*16+q4*4+r, col q=l15
    f32x4 sf[4];
    for (int nt = 0; nt < 4; ++nt) sf[nt] = zero;
    for (int kk = 0; kk < 2; ++kk)
      for (int nt = 0; nt < 4; ++nt) {
        b16x8 bk =
            *(const b16x8*)(Klds + (nt * 16 + l15) * PAD_ + kk * 32 + q4 * 8);
        sf[nt] = mfma16(bk, aq[kk], sf[nt]);
      }

    // fixed-max softmax; mask indexed by key (row) -> broadcast float4
    for (int nt = 0; nt < 4; ++nt) {
      const float4 mk = *(const float4*)(Mlds + key0 + nt * 16 + q4 * 4);
      float p0 = __builtin_amdgcn_exp2f(sf[nt][0] * c1 + mk.x);
      float p1 = __builtin_amdgcn_exp2f(sf[nt][1] * c1 + mk.y);
      float p2 = __builtin_amdgcn_exp2f(sf[nt][2] * c1 + mk.z);
      float p3 = __builtin_amdgcn_exp2f(sf[nt][3] * c1 + mk.w);
      lsum += (p0 + p1) + (p2 + p3);
      uint2 pk;
      pk.x = ((u32)bfbits(p1) << 16) | bfbits(p0);
      pk.y = ((u32)bfbits(p3) << 16) | bfbits(p2);
      // P[q=l15][key=nt*16+q4*4 .. +3]: 4 consecutive keys, one b64 write
      *(uint2*)(Pw + l15 * QPAD_ + nt * 16 + q4 * 4) = pk;
    }
    // wave-private handoff: drain the 4 P writes only
    asm volatile("s_waitcnt lgkmcnt(0)" ::: "memory");

    // O^T += V^T·P: A=V-frag (same read as before), B=P-frag (b128 row read)
    for (int kk = 0; kk < 2; ++kk) {
      b16x8 bp = *(const b16x8*)(Pw + l15 * QPAD_ + kk * 32 + q4 * 8);
      for (int nt = 0; nt < 4; ++nt) {
        b16x8 vb =
            *(const b16x8*)(Vlds + (nt * 16 + l15) * PAD_ + kk * 32 + q4 * 8);
        acc[nt] = mfma16(vb, bp, acc[nt]);
      }
    }
  }

  // row-sum: quads hold disjoint key quarters -> reduce across quads
  lsum += __shfl_xor(lsum, 16);
  lsum += __shfl_xor(lsum, 32);
  const float inv = 1.0f / lsum;

  // epilogue: lane writes 4 consecutive d at fixed row s -> dwordx2 stores
  const int srw = q0 + w * 16 + l15;
  u16* crow = ctx + ((size_t)(b * S_ + srw)) * D_ + h * 64;
  for (int nt = 0; nt < 4; ++nt) {
    uint2 pk;
    pk.x = ((u32)bfbits(acc[nt][1] * inv) << 16) | bfbits(acc[nt][0] * inv);
    pk.y = ((u32)bfbits(acc[nt][3] * inv) << 16) | bfbits(acc[nt][2] * inv);
    *(uint2*)(crow + nt * 16 + q4 * 4) = pk;
  }
}

// ---------------------------------------------------------------------------
// Output projection + bias + residual(x f32) -> y (fp32).
// 128x128 tiles: grid 512 = 64by x 8bx = exactly 2 blocks/CU, one round.
// XCD swizzle: XCD x owns by {8x..8x+7} (A band 2MB) + full wto (2MB) = 4MB.
// ---------------------------------------------------------------------------
__global__ __launch_bounds__(256, 2) void out_gemm_kernel(
    const u16* __restrict__ ctx, const u16* __restrict__ wto,
    const float* __restrict__ bo, const float* __restrict__ x,
    float* __restrict__ y) {
  __shared__ __align__(16) u16 lds[2 * BUF128_];  // 64 KB
  const int wg = blockIdx.x;
  const int xcd = wg & 7;
  const int s = wg >> 3;             // 0..63
  const int by = xcd * 8 + (s & 7);  // 0..63
  const int bx = s >> 3;             // 0..7
  const int m0 = by * 128, n0 = bx * 128;

  f32x4 acc[4][4];
  gemm128_mainloop(ctx, wto, D_, m0, n0, lds, acc);

  const int t = threadIdx.x;
  const int lane = t & 63, w = t >> 6;
  const int l15 = lane & 15, q4 = lane >> 4;
  const int mwave = (w >> 1) * 64, nwave = (w & 1) * 64;

  for (int nt = 0; nt < 4; ++nt) {
    const int n = n0 + nwave + nt * 16 + l15;
    const float bias = bo[n];
    for (int mt = 0; mt < 4; ++mt) {
      for (int r = 0; r < 4; ++r) {
        const int m = m0 + mwave + mt * 16 + q4 * 4 + r;
        y[(size_t)m * D_ + n] = acc[mt][nt][r] + bias + x[(size_t)m * D_ + n];
      }
    }
  }
}

// ---------------------------------------------------------------------------
// Row LayerNorm: one block per row of 1024, f32 in, f32 out
// ---------------------------------------------------------------------------
__global__ __launch_bounds__(256) void ln_kernel(const float* __restrict__ y,
                                                 const float* __restrict__ g,
                                                 const float* __restrict__ be,
                                                 float* __restrict__ out) {
  const int row = blockIdx.x, t = threadIdx.x;
  const float* yr = y + (size_t)row * D_;
  const float4 v = *(const float4*)(yr + t * 4);
  float s = v.x + v.y + v.z + v.w;
  float ss = v.x * v.x + v.y * v.y + v.z * v.z + v.w * v.w;
  for (int off = 1; off < 64; off <<= 1) {
    s += __shfl_xor(s, off);
    ss += __shfl_xor(ss, off);
  }
  __shared__ float red[8];
  const int w = t >> 6, lane = t & 63;
  if (lane == 0) {
    red[w] = s;
    red[4 + w] = ss;
  }
  __syncthreads();
  s = red[0] + red[1] + red[2] + red[3];
  ss = red[4] + red[5] + red[6] + red[7];
  const float mu = s * (1.f / 1024.f);
  const float var = ss * (1.f / 1024.f) - mu * mu;
  const float rs = rsqrtf(var + 1e-6f);
  const int c = t * 4;
  const float4 gv = *(const float4*)(g + c);
  const float4 bv = *(const float4*)(be + c);
  float4 o;
  o.x = (v.x - mu) * rs * gv.x + bv.x;
  o.y = (v.y - mu) * rs * gv.y + bv.y;
  o.z = (v.z - mu) * rs * gv.z + bv.z;
  o.w = (v.w - mu) * rs * gv.w + bv.w;
  *(float4*)(out + (size_t)row * D_ + c) = o;
}

// ---------------------------------------------------------------------------
extern "C" void kernel_launch(void* const* d_in, const int* in_sizes, int n_in,
                              void* d_out, int out_size, void* d_ws,
                              size_t ws_size, hipStream_t stream) {
  const float* x = (const float*)d_in[0];
  const int* mask = (const int*)d_in[1];
  const float* wq = (const float*)d_in[2];
  const float* bq = (const float*)d_in[3];
  const float* wk = (const float*)d_in[4];
  const float* bk = (const float*)d_in[5];
  const float* wv = (const float*)d_in[6];
  const float* bv = (const float*)d_in[7];
  const float* wo = (const float*)d_in[8];
  const float* bo = (const float*)d_in[9];
  const float* gamma = (const float*)d_in[10];
  const float* beta = (const float*)d_in[11];
  float* out = (float*)d_out;

  char* ws = (char*)d_ws;
  const size_t MB = 1024ull * 1024ull;
  u16* wtq = (u16*)(ws + 0 * MB);  // wtq/wtk/wtv contiguous = fused [3072][1024]
  u16* wtk = (u16*)(ws + 2 * MB);
  u16* wtv = (u16*)(ws + 4 * MB);
  u16* wto = (u16*)(ws + 6 * MB);
  u16* xb = (u16*)(ws + 8 * MB);    // 16MB bf16 x; dead after qkv_gemm
  u16* ctx = (u16*)(ws + 8 * MB);   // aliases xb (written by attn)
  u16* Qb = (u16*)(ws + 24 * MB);   // 16MB; dead after attn
  u16* Kb = (u16*)(ws + 40 * MB);   // 16MB; dead after attn
  u16* VTb = (u16*)(ws + 56 * MB);  // 16MB
  float* y = (float*)(ws + 24 * MB);  // 32MB fp32, aliases Qb+Kb
  // total: 72MB

  wconv_kernel<<<dim3(32, 32, 4), dim3(32, 32), 0, stream>>>(
      wq, wk, wv, wo, wtq, wtk, wtv, wto);
  xconv_kernel<<<8192, 256, 0, stream>>>(x, xb);
  qkv_gemm_kernel<<<1536, 256, 0, stream>>>(xb, wtq, bq, bk, bv, Qb, Kb, VTb);
  attn_kernel<<<1024, 512, 0, stream>>>(Qb, Kb, VTb, mask, ctx);
  out_gemm_kernel<<<512, 256, 0, stream>>>(ctx, wto, bo, x, y);
  ln_kernel<<<8192, 256, 0, stream>>>(y, gamma, beta, out);
}

// Round 13
// 273.178 us; speedup vs baseline: 1.0279x; 1.0279x over previous
//
#include <hip/hip_runtime.h>
#include <stdint.h>

typedef unsigned short u16;
typedef unsigned int u32;
typedef __bf16 b16x8 __attribute__((ext_vector_type(8)));
typedef float f32x4 __attribute__((ext_vector_type(4)));

#define B_ 8
#define S_ 1024
#define H_ 16
#define HD_ 64
#define D_ 1024
#define M_ 8192

__device__ __forceinline__ u16 f2bf(float f) {
  u32 u = __float_as_uint(f);
  return (u16)((u + 0x7fffu + ((u >> 16) & 1u)) >> 16);
}
__device__ __forceinline__ u16 bfbits(float f) {
  union {
    __bf16 b;
    u16 u;
  } c;
  c.b = (__bf16)f;  // native V_CVT (RNE)
  return c.u;
}

__device__ __forceinline__ f32x4 mfma16(b16x8 a, b16x8 b, f32x4 c) {
  return __builtin_amdgcn_mfma_f32_16x16x32_bf16(a, b, c, 0, 0, 0);
}

// async global->LDS, 16B per lane. LDS dest = wave-uniform base + lane*16.
__device__ __forceinline__ void cp16(const u16* g, u16* l) {
  __builtin_amdgcn_global_load_lds(
      (const __attribute__((address_space(1))) u32*)(g),
      (__attribute__((address_space(3))) u32*)(l), 16, 0, 0);
}

// ---------------------------------------------------------------------------
// Weight convert+transpose: WT[n][k] = bf16(W[k][n]), W f32 1024x1024.
// wtq/wtk/wtv land contiguous in ws -> fused B matrix [3072][1024] for QKV.
// ---------------------------------------------------------------------------
__global__ __launch_bounds__(1024) void wconv_kernel(
    const float* __restrict__ w0, const float* __restrict__ w1,
    const float* __restrict__ w2, const float* __restrict__ w3,
    u16* __restrict__ t0, u16* __restrict__ t1, u16* __restrict__ t2,
    u16* __restrict__ t3) {
  __shared__ float tile[32][33];
  const int z = blockIdx.z;
  const float* src = (z == 0) ? w0 : (z == 1) ? w1 : (z == 2) ? w2 : w3;
  u16* dst = (z == 0) ? t0 : (z == 1) ? t1 : (z == 2) ? t2 : t3;
  const int tx = threadIdx.x, ty = threadIdx.y;
  const int x0 = blockIdx.x * 32, y0 = blockIdx.y * 32;
  tile[ty][tx] = src[(size_t)(y0 + ty) * D_ + x0 + tx];
  __syncthreads();
  dst[(size_t)(x0 + ty) * D_ + y0 + tx] = f2bf(tile[tx][ty]);
}

// ---------------------------------------------------------------------------
// x convert: f32 -> bf16, 8M elements, 4/thread
// ---------------------------------------------------------------------------
__global__ __launch_bounds__(256) void xconv_kernel(const float* __restrict__ x,
                                                    u16* __restrict__ xb) {
  const size_t i = ((size_t)blockIdx.x * 256 + threadIdx.x) * 4;
  const float4 v = *(const float4*)(x + i);
  u16 o[4] = {f2bf(v.x), f2bf(v.y), f2bf(v.z), f2bf(v.w)};
  uint2 pack;
  pack.x = ((u32)o[1] << 16) | o[0];
  pack.y = ((u32)o[3] << 16) | o[2];
  *(uint2*)(xb + i) = pack;
}

// ---------------------------------------------------------------------------
// 128x128 GEMM mainloop, BK=64, 256 threads (4 waves, 2Mx2N, wave 64x64),
// double-buffered LDS 2x32KB = 64KB -> 2 blocks/CU (verified round 12:
// qkv improved vs 1-block/CU 256-wide tiles; co-residency fills barrier
// drains with the other block's waves).
// ---------------------------------------------------------------------------
#define BUF128_ 16384  // u16 per buffer: A 128x64 (8192) + B 128x64 (8192)

__device__ __forceinline__ void gemm128_mainloop(
    const u16* __restrict__ A, const u16* __restrict__ BT, int K, int m0,
    int n0, u16* lds, f32x4 (&acc)[4][4]) {
  const int t = threadIdx.x;
  const int lane = t & 63;
  const int l15 = lane & 15;
  const int q4 = lane >> 4;
  const int w = t >> 6;            // 0..3
  const int mwave = (w >> 1) * 64; // 2M x 2N wave grid, 64x64 each
  const int nwave = (w & 1) * 64;

  const f32x4 zero = {0.f, 0.f, 0.f, 0.f};
#pragma unroll
  for (int mt = 0; mt < 4; ++mt)
#pragma unroll
    for (int nt = 0; nt < 4; ++nt) acc[mt][nt] = zero;

  const int rbase = t >> 3;                      // 0..31
  const int scol = ((t & 7) ^ (rbase & 7)) * 8;  // pre-swizzled global col
  const u16* Ag = A + (size_t)(m0 + rbase) * K + scol;
  const u16* Bg = BT + (size_t)(n0 + rbase) * K + scol;
  const int sx = l15 & 7;

  // one stage = 8 cp16/thread (4x A 32-row pieces + 4x B)
  auto STAGE = [&](int kt, int bufi) {
    u16* Ab = lds + bufi * BUF128_;
    u16* Bb = Ab + 8192;
    const int k0 = kt * 64;
#pragma unroll
    for (int c = 0; c < 4; ++c)
      cp16(Ag + (size_t)(c * 32) * K + k0, Ab + c * 2048 + t * 8);
#pragma unroll
    for (int c = 0; c < 4; ++c)
      cp16(Bg + (size_t)(c * 32) * K + k0, Bb + c * 2048 + t * 8);
  };

  const int NT = K / 64;  // 16
  STAGE(0, 0);

  int cur = 0;
  for (int kt = 0; kt < NT; ++kt) {
    if (kt + 1 < NT) STAGE(kt + 1, cur ^ 1);  // issue BEFORE the wait
    // readiness of buf[cur]: retire only the oldest 8 (counted vmcnt)
    if (kt + 1 < NT)
      asm volatile("s_waitcnt vmcnt(8)" ::: "memory");
    else
      asm volatile("s_waitcnt vmcnt(0)" ::: "memory");
    asm volatile("s_barrier" ::: "memory");

    const u16* Ab = lds + cur * BUF128_;
    const u16* Bb = Ab + 8192;

    // all 16 fragment reads for both kk halves, back-to-back (kk0 first)
    b16x8 af[4][2], bf2[4][2];
#pragma unroll
    for (int kk = 0; kk < 2; ++kk) {
      const int cc = ((kk * 4 + q4) ^ sx) * 8;
#pragma unroll
      for (int mt = 0; mt < 4; ++mt)
        af[mt][kk] = *(const b16x8*)(Ab + (mwave + mt * 16 + l15) * 64 + cc);
#pragma unroll
      for (int nt = 0; nt < 4; ++nt)
        bf2[nt][kk] = *(const b16x8*)(Bb + (nwave + nt * 16 + l15) * 64 + cc);
    }
    __builtin_amdgcn_sched_barrier(0);

    // kk0 MFMA (compiler inserts counted lgkm waits)
    __builtin_amdgcn_s_setprio(1);
#pragma unroll
    for (int mt = 0; mt < 4; ++mt)
#pragma unroll
      for (int nt = 0; nt < 4; ++nt)
        acc[mt][nt] = mfma16(af[mt][0], bf2[nt][0], acc[mt][nt]);
    __builtin_amdgcn_s_setprio(0);

    // all waves' reads of buf[cur] complete before anyone can restage it
    asm volatile("s_waitcnt lgkmcnt(0)" ::: "memory");
    asm volatile("s_barrier" ::: "memory");

    __builtin_amdgcn_s_setprio(1);
#pragma unroll
    for (int mt = 0; mt < 4; ++mt)
#pragma unroll
      for (int nt = 0; nt < 4; ++nt)
        acc[mt][nt] = mfma16(af[mt][1], bf2[nt][1], acc[mt][nt]);
    __builtin_amdgcn_s_setprio(0);

    cur ^= 1;
  }
}

// ---------------------------------------------------------------------------
// Fused QKV projection (128x128 tiles, verified round 12): grid 1536 =
// 64by x 24bx, 2 blocks/CU -> 3 rounds. XCD x owns by {8x..8x+7}.
// z=0 -> Q [B,H,S,HD], z=1 -> K [B,H,S,HD], z=2 -> V^T [B,H,HD,S]
// ---------------------------------------------------------------------------
__global__ __launch_bounds__(256, 2) void qkv_gemm_kernel(
    const u16* __restrict__ xb, const u16* __restrict__ wt3,
    const float* __restrict__ bq, const float* __restrict__ bk,
    const float* __restrict__ bv, u16* __restrict__ Q, u16* __restrict__ Kb,
    u16* __restrict__ VT) {
  __shared__ __align__(16) u16 lds[2 * BUF128_];  // 64 KB
  const int wg = blockIdx.x;
  const int xcd = wg & 7;
  const int s = wg >> 3;             // 0..191
  const int by = xcd * 8 + (s & 7);  // 0..63: 8 A-panels pinned per XCD
  const int bx = s >> 3;             // 0..23: B streams
  const int m0 = by * 128;
  const int n0 = bx * 128;  // fused col base 0..2944

  f32x4 acc[4][4];
  gemm128_mainloop(xb, wt3, D_, m0, n0, lds, acc);

  const int t = threadIdx.x;
  const int lane = t & 63, w = t >> 6;
  const int l15 = lane & 15, q4 = lane >> 4;
  const int mwave = (w >> 1) * 64, nwave = (w & 1) * 64;

  const int z = n0 >> 10;  // uniform per block
  u16* out = (z == 0) ? Q : (z == 1) ? Kb : VT;
  const float* bias = (z == 0) ? bq : (z == 1) ? bk : bv;

  for (int nt = 0; nt < 4; ++nt) {
    const int nf = n0 + nwave + nt * 16 + l15;  // fused col
    const int n1 = nf & 1023;                   // col within matrix
    const float bias_v = bias[n1];
    const int h = n1 >> 6, hd = n1 & 63;
    for (int mt = 0; mt < 4; ++mt) {
      for (int r = 0; r < 4; ++r) {
        const int m = m0 + mwave + mt * 16 + q4 * 4 + r;
        const int b = m >> 10, ss = m & 1023;
        const float v = acc[mt][nt][r] + bias_v;
        size_t idx;
        if (z < 2)
          idx = (((size_t)(b * H_ + h)) * S_ + ss) * HD_ + hd;
        else
          idx = (((size_t)(b * H_ + h)) * HD_ + hd) * S_ + ss;
        out[idx] = f2bf(v);
      }
    }
  }
}

// ---------------------------------------------------------------------------
// 256x128 GEMM mainloop (round-11 verified config, 4Mx2N wave 64x64) --
// restored for out_gemm (round-12's 128^2 out_gemm coincided with a ~5us
// total regression; this is a revert to the measured-good form).
// ---------------------------------------------------------------------------
#define ABUF_ 16384  // u16: 256x64 A tile
#define BBUF_ 8192   // u16: 128x64 B tile
#define BUFSZ_ (ABUF_ + BBUF_)

__device__ __forceinline__ void gemm256x128_mainloop(
    const u16* __restrict__ A, const u16* __restrict__ BT, int K, int m0,
    int n0, u16* lds, f32x4 (&acc)[4][4]) {
  const int t = threadIdx.x;
  const int lane = t & 63;
  const int l15 = lane & 15;
  const int q4 = lane >> 4;
  const int w = t >> 6;
  const int wm = w >> 1;  // 0..3 -> 64-row slice
  const int wn = w & 1;   // 0..1 -> 64-col slice

  const f32x4 zero = {0.f, 0.f, 0.f, 0.f};
#pragma unroll
  for (int mt = 0; mt < 4; ++mt)
#pragma unroll
    for (int nt = 0; nt < 4; ++nt) acc[mt][nt] = zero;

  const int rbase = t >> 3;                      // 0..63
  const int scol = ((t & 7) ^ (rbase & 7)) * 8;  // pre-swizzled global col
  const u16* Ag = A + (size_t)(m0 + rbase) * K + scol;
  const u16* Bg = BT + (size_t)(n0 + rbase) * K + scol;
  const int sx = l15 & 7;

  auto STAGE = [&](int kt, int bufi) {
    u16* Ab = lds + bufi * BUFSZ_;
    u16* Bb = Ab + ABUF_;
    const int k0 = kt * 64;
#pragma unroll
    for (int c = 0; c < 4; ++c)
      cp16(Ag + (size_t)(c * 64) * K + k0, Ab + c * 4096 + t * 8);
#pragma unroll
    for (int c = 0; c < 2; ++c)
      cp16(Bg + (size_t)(c * 64) * K + k0, Bb + c * 4096 + t * 8);
  };

  const int NT = K / 64;  // 16
  STAGE(0, 0);
  STAGE(1, 1);

  int cur = 0;
  for (int kt = 0; kt < NT; ++kt) {
    if (kt + 2 < NT) {
      int nb = cur + 2;
      if (nb >= 3) nb -= 3;
      STAGE(kt + 2, nb);
    }
    if (kt + 2 < NT)
      asm volatile("s_waitcnt vmcnt(12)" ::: "memory");
    else if (kt + 1 < NT)
      asm volatile("s_waitcnt vmcnt(6)" ::: "memory");
    else
      asm volatile("s_waitcnt vmcnt(0)" ::: "memory");
    asm volatile("s_barrier" ::: "memory");

    const u16* Ab = lds + cur * BUFSZ_;
    const u16* Bb = Ab + ABUF_;

    b16x8 af[4][2], bf2[4][2];
#pragma unroll
    for (int kk = 0; kk < 2; ++kk) {
      const int cc = ((kk * 4 + q4) ^ sx) * 8;
#pragma unroll
      for (int mt = 0; mt < 4; ++mt)
        af[mt][kk] = *(const b16x8*)(Ab + (wm * 64 + mt * 16 + l15) * 64 + cc);
#pragma unroll
      for (int nt = 0; nt < 4; ++nt)
        bf2[nt][kk] = *(const b16x8*)(Bb + (wn * 64 + nt * 16 + l15) * 64 + cc);
    }
    __builtin_amdgcn_sched_barrier(0);

    __builtin_amdgcn_s_setprio(1);
#pragma unroll
    for (int mt = 0; mt < 4; ++mt)
#pragma unroll
      for (int nt = 0; nt < 4; ++nt)
        acc[mt][nt] = mfma16(af[mt][0], bf2[nt][0], acc[mt][nt]);
    __builtin_amdgcn_s_setprio(0);

    asm volatile("s_waitcnt lgkmcnt(0)" ::: "memory");
    asm volatile("s_barrier" ::: "memory");

    __builtin_amdgcn_s_setprio(1);
#pragma unroll
    for (int mt = 0; mt < 4; ++mt)
#pragma unroll
      for (int nt = 0; nt < 4; ++nt)
        acc[mt][nt] = mfma16(af[mt][1], bf2[nt][1], acc[mt][nt]);
    __builtin_amdgcn_s_setprio(0);

    ++cur;
    if (cur == 3) cur = 0;
  }
}

// ---------------------------------------------------------------------------
// Flash attention, fixed-max softmax, transposed-score formulation.
// QBLK=128 (512 threads, 8 waves), verified round-6.
// ROUND-13 CHANGE: KVBLK 64 -> 128. Stage K[128][64] + V^T[64][128] per
// outer iter (8 iters, 16 barriers total vs 32), then TWO 64-key sub-rounds
// (ks=0,1) between one barrier pair -- each sub-round is the verified j-body
// offset by ks*64. P buffer (wave-private QPlds slice) is reused across
// halves: in-order per-wave DS + existing lgkm drains order write->read->
// write. LDS 57.3KB -> still 2 blocks/CU.
// ---------------------------------------------------------------------------
#define PAD_ 68    // K row stride (verified conflict-free)
#define VPAD_ 136  // V row stride: 128 keys + 8 (272B, 16B-aligned rows)
#define QPAD_ 72   // Q/P row stride (144B)
__global__ __launch_bounds__(512) void attn_kernel(
    const u16* __restrict__ Q, const u16* __restrict__ Kb,
    const u16* __restrict__ VT, const int* __restrict__ mask,
    u16* __restrict__ ctx) {
  __shared__ __align__(16) u16 QPlds[128 * QPAD_];  // 18432 B
  __shared__ __align__(16) u16 Klds[128 * PAD_];    // 17408 B: [key128][d64]
  __shared__ __align__(16) u16 Vlds[64 * VPAD_];    // 17408 B: [d64][key128]
  __shared__ __align__(16) float Mlds[1024];        // 4096 B

  const int t = threadIdx.x;
  const int lane = t & 63, w = t >> 6;  // w 0..7
  const int l15 = lane & 15, q4 = lane >> 4;
  const int id = blockIdx.x;
  const int bh = id & 127;  // XCD = id%8 = bh%8 -> q-tiles of a bh co-locate
  const int b = bh >> 4, h = bh & 15;
  const int q0 = (id >> 7) * 128;  // 8 q-tiles of 128 rows

  const u16* Qbh = Q + (size_t)bh * S_ * HD_;
  const u16* Kbh = Kb + (size_t)bh * S_ * HD_;
  const u16* Vbh = VT + (size_t)bh * S_ * HD_;  // [HD][S]
  const int* maskb = mask + b * S_;

  const int srow = t >> 3, scol = (t & 7) * 8;  // srow 0..63
  {  // stage Q tile [128][64] + mask into LDS
    b16x8 q0v = *(const b16x8*)(Qbh + (size_t)(q0 + srow) * HD_ + scol);
    b16x8 q1v = *(const b16x8*)(Qbh + (size_t)(q0 + srow + 64) * HD_ + scol);
    const int2 mv = *(const int2*)(maskb + t * 2);
    *(b16x8*)(QPlds + srow * QPAD_ + scol) = q0v;
    *(b16x8*)(QPlds + (srow + 64) * QPAD_ + scol) = q1v;
    float2 mf;
    mf.x = -14427.0f * (float)mv.x;
    mf.y = -14427.0f * (float)mv.y;
    *(float2*)(Mlds + t * 2) = mf;
  }
  __syncthreads();
  // Q B-frags (lane holds Q[q=l15][d=q4*8+j]), wave-private rows
  b16x8 aq[2];
  aq[0] = *(const b16x8*)(QPlds + (w * 16 + l15) * QPAD_ + q4 * 8);
  aq[1] = *(const b16x8*)(QPlds + (w * 16 + l15) * QPAD_ + 32 + q4 * 8);

  const f32x4 zero = {0.f, 0.f, 0.f, 0.f};
  f32x4 acc[4];  // O^T tiles: acc[nt] row d=nt*16+q4*4+r, col q=l15
  for (int nt = 0; nt < 4; ++nt) acc[nt] = zero;
  float lsum = 0.f;                  // partial row-sum for q=l15
  u16* Pw = QPlds + w * 16 * QPAD_;  // wave-private P: [q(16)][key(64)]
  const float c1 = 0.18033688f;      // 0.125 * log2(e)

  // prologue prefetch for j=0: K keys 0..127 (2 rows/thread), V d-row srow
  // cols 0..63 and 64..127
  b16x8 kv0 = *(const b16x8*)(Kbh + (size_t)srow * HD_ + scol);
  b16x8 kv1 = *(const b16x8*)(Kbh + (size_t)(srow + 64) * HD_ + scol);
  b16x8 vv0 = *(const b16x8*)(Vbh + (size_t)srow * S_ + scol);
  b16x8 vv1 = *(const b16x8*)(Vbh + (size_t)srow * S_ + 64 + scol);

  for (int j = 0; j < 8; ++j) {
    const int key0 = j * 128;
    __syncthreads();  // (A) prior iteration's K/V LDS reads complete
    *(b16x8*)(Klds + srow * PAD_ + scol) = kv0;
    *(b16x8*)(Klds + (srow + 64) * PAD_ + scol) = kv1;
    *(b16x8*)(Vlds + srow * VPAD_ + scol) = vv0;
    *(b16x8*)(Vlds + srow * VPAD_ + 64 + scol) = vv1;
    __syncthreads();  // (B) staging visible

    if (j < 7) {  // prefetch next tile's K/V during compute
      const int kn = key0 + 128;
      kv0 = *(const b16x8*)(Kbh + (size_t)(kn + srow) * HD_ + scol);
      kv1 = *(const b16x8*)(Kbh + (size_t)(kn + srow + 64) * HD_ + scol);
      vv0 = *(const b16x8*)(Vbh + (size_t)srow * S_ + kn + scol);
      vv1 = *(const b16x8*)(Vbh + (size_t)srow * S_ + kn + 64 + scol);
    }

#pragma unroll
    for (int ks = 0; ks < 2; ++ks) {  // two 64-key sub-rounds, no barriers
      // S^T = K·Q^T: sf[nt] rows key=ks*64+nt*16+q4*4+r, col q=l15
      f32x4 sf[4];
      for (int nt = 0; nt < 4; ++nt) sf[nt] = zero;
      for (int kk = 0; kk < 2; ++kk)
        for (int nt = 0; nt < 4; ++nt) {
          b16x8 bk = *(const b16x8*)(Klds + (ks * 64 + nt * 16 + l15) * PAD_ +
                                     kk * 32 + q4 * 8);
          sf[nt] = mfma16(bk, aq[kk], sf[nt]);
        }

      // fixed-max softmax; mask indexed by key (row) -> broadcast float4
      for (int nt = 0; nt < 4; ++nt) {
        const float4 mk =
            *(const float4*)(Mlds + key0 + ks * 64 + nt * 16 + q4 * 4);
        float p0 = __builtin_amdgcn_exp2f(sf[nt][0] * c1 + mk.x);
        float p1 = __builtin_amdgcn_exp2f(sf[nt][1] * c1 + mk.y);
        float p2 = __builtin_amdgcn_exp2f(sf[nt][2] * c1 + mk.z);
        float p3 = __builtin_amdgcn_exp2f(sf[nt][3] * c1 + mk.w);
        lsum += (p0 + p1) + (p2 + p3);
        uint2 pk;
        pk.x = ((u32)bfbits(p1) << 16) | bfbits(p0);
        pk.y = ((u32)bfbits(p3) << 16) | bfbits(p2);
        // P[q=l15][key=nt*16+q4*4 .. +3]: one b64 write
        *(uint2*)(Pw + l15 * QPAD_ + nt * 16 + q4 * 4) = pk;
      }
      // wave-private handoff: drain the 4 P writes only
      asm volatile("s_waitcnt lgkmcnt(0)" ::: "memory");

      // O^T += V^T·P: A=V-frag (col ks*64+..), B=P-frag (b128 row read)
      for (int kk = 0; kk < 2; ++kk) {
        b16x8 bp = *(const b16x8*)(Pw + l15 * QPAD_ + kk * 32 + q4 * 8);
        for (int nt = 0; nt < 4; ++nt) {
          b16x8 vb = *(const b16x8*)(Vlds + (nt * 16 + l15) * VPAD_ + ks * 64 +
                                     kk * 32 + q4 * 8);
          acc[nt] = mfma16(vb, bp, acc[nt]);
        }
      }
    }
  }

  // row-sum: quads hold disjoint key quarters -> reduce across quads
  lsum += __shfl_xor(lsum, 16);
  lsum += __shfl_xor(lsum, 32);
  const float inv = 1.0f / lsum;

  // epilogue: lane writes 4 consecutive d at fixed row s -> dwordx2 stores
  const int srw = q0 + w * 16 + l15;
  u16* crow = ctx + ((size_t)(b * S_ + srw)) * D_ + h * 64;
  for (int nt = 0; nt < 4; ++nt) {
    uint2 pk;
    pk.x = ((u32)bfbits(acc[nt][1] * inv) << 16) | bfbits(acc[nt][0] * inv);
    pk.y = ((u32)bfbits(acc[nt][3] * inv) << 16) | bfbits(acc[nt][2] * inv);
    *(uint2*)(crow + nt * 16 + q4 * 4) = pk;
  }
}

// ---------------------------------------------------------------------------
// Output projection + bias + residual(x f32) -> y (fp32).
// Round-11 verified config restored: 256x128 tiles, grid 256 = 32by x 8bx
// = 1 block/CU, one round. XCD x owns by {4x..4x+3} (A 2MB) + wto (2MB).
// ---------------------------------------------------------------------------
__global__ __launch_bounds__(512, 2) void out_gemm_kernel(
    const u16* __restrict__ ctx, const u16* __restrict__ wto,
    const float* __restrict__ bo, const float* __restrict__ x,
    float* __restrict__ y) {
  __shared__ __align__(16) u16 lds[3 * BUFSZ_];  // 144 KB
  const int wg = blockIdx.x;
  const int xcd = wg & 7;
  const int s = wg >> 3;             // 0..31
  const int by = xcd * 4 + (s & 3);  // 0..31
  const int bx = s >> 2;             // 0..7
  const int m0 = by * 256, n0 = bx * 128;

  f32x4 acc[4][4];
  gemm256x128_mainloop(ctx, wto, D_, m0, n0, lds, acc);

  const int t = threadIdx.x;
  const int lane = t & 63, w = t >> 6;
  const int l15 = lane & 15, q4 = lane >> 4;
  const int wm = w >> 1, wn = w & 1;

  for (int nt = 0; nt < 4; ++nt) {
    const int n = n0 + wn * 64 + nt * 16 + l15;
    const float bias = bo[n];
    for (int mt = 0; mt < 4; ++mt) {
      for (int r = 0; r < 4; ++r) {
        const int m = m0 + wm * 64 + mt * 16 + q4 * 4 + r;
        y[(size_t)m * D_ + n] = acc[mt][nt][r] + bias + x[(size_t)m * D_ + n];
      }
    }
  }
}

// ---------------------------------------------------------------------------
// Row LayerNorm: one block per row of 1024, f32 in, f32 out
// ---------------------------------------------------------------------------
__global__ __launch_bounds__(256) void ln_kernel(const float* __restrict__ y,
                                                 const float* __restrict__ g,
                                                 const float* __restrict__ be,
                                                 float* __restrict__ out) {
  const int row = blockIdx.x, t = threadIdx.x;
  const float* yr = y + (size_t)row * D_;
  const float4 v = *(const float4*)(yr + t * 4);
  float s = v.x + v.y + v.z + v.w;
  float ss = v.x * v.x + v.y * v.y + v.z * v.z + v.w * v.w;
  for (int off = 1; off < 64; off <<= 1) {
    s += __shfl_xor(s, off);
    ss += __shfl_xor(ss, off);
  }
  __shared__ float red[8];
  const int w = t >> 6, lane = t & 63;
  if (lane == 0) {
    red[w] = s;
    red[4 + w] = ss;
  }
  __syncthreads();
  s = red[0] + red[1] + red[2] + red[3];
  ss = red[4] + red[5] + red[6] + red[7];
  const float mu = s * (1.f / 1024.f);
  const float var = ss * (1.f / 1024.f) - mu * mu;
  const float rs = rsqrtf(var + 1e-6f);
  const int c = t * 4;
  const float4 gv = *(const float4*)(g + c);
  const float4 bv = *(const float4*)(be + c);
  float4 o;
  o.x = (v.x - mu) * rs * gv.x + bv.x;
  o.y = (v.y - mu) * rs * gv.y + bv.y;
  o.z = (v.z - mu) * rs * gv.z + bv.z;
  o.w = (v.w - mu) * rs * gv.w + bv.w;
  *(float4*)(out + (size_t)row * D_ + c) = o;
}

// ---------------------------------------------------------------------------
extern "C" void kernel_launch(void* const* d_in, const int* in_sizes, int n_in,
                              void* d_out, int out_size, void* d_ws,
                              size_t ws_size, hipStream_t stream) {
  const float* x = (const float*)d_in[0];
  const int* mask = (const int*)d_in[1];
  const float* wq = (const float*)d_in[2];
  const float* bq = (const float*)d_in[3];
  const float* wk = (const float*)d_in[4];
  const float* bk = (const float*)d_in[5];
  const float* wv = (const float*)d_in[6];
  const float* bv = (const float*)d_in[7];
  const float* wo = (const float*)d_in[8];
  const float* bo = (const float*)d_in[9];
  const float* gamma = (const float*)d_in[10];
  const float* beta = (const float*)d_in[11];
  float* out = (float*)d_out;

  char* ws = (char*)d_ws;
  const size_t MB = 1024ull * 1024ull;
  u16* wtq = (u16*)(ws + 0 * MB);  // wtq/wtk/wtv contiguous = fused [3072][1024]
  u16* wtk = (u16*)(ws + 2 * MB);
  u16* wtv = (u16*)(ws + 4 * MB);
  u16* wto = (u16*)(ws + 6 * MB);
  u16* xb = (u16*)(ws + 8 * MB);    // 16MB bf16 x; dead after qkv_gemm
  u16* ctx = (u16*)(ws + 8 * MB);   // aliases xb (written by attn)
  u16* Qb = (u16*)(ws + 24 * MB);   // 16MB; dead after attn
  u16* Kb = (u16*)(ws + 40 * MB);   // 16MB; dead after attn
  u16* VTb = (u16*)(ws + 56 * MB);  // 16MB
  float* y = (float*)(ws + 24 * MB);  // 32MB fp32, aliases Qb+Kb
  // total: 72MB

  wconv_kernel<<<dim3(32, 32, 4), dim3(32, 32), 0, stream>>>(
      wq, wk, wv, wo, wtq, wtk, wtv, wto);
  xconv_kernel<<<8192, 256, 0, stream>>>(x, xb);
  qkv_gemm_kernel<<<1536, 256, 0, stream>>>(xb, wtq, bq, bk, bv, Qb, Kb, VTb);
  attn_kernel<<<1024, 512, 0, stream>>>(Qb, Kb, VTb, mask, ctx);
  out_gemm_kernel<<<256, 512, 0, stream>>>(ctx, wto, bo, x, y);
  ln_kernel<<<8192, 256, 0, stream>>>(y, gamma, beta, out);
}

// Round 14
// 271.552 us; speedup vs baseline: 1.0340x; 1.0060x over previous
//
#include <hip/hip_runtime.h>
#include <stdint.h>

typedef unsigned short u16;
typedef unsigned int u32;
typedef __bf16 b16x8 __attribute__((ext_vector_type(8)));
typedef float f32x4 __attribute__((ext_vector_type(4)));

#define B_ 8
#define S_ 1024
#define H_ 16
#define HD_ 64
#define D_ 1024
#define M_ 8192

__device__ __forceinline__ u16 f2bf(float f) {
  u32 u = __float_as_uint(f);
  return (u16)((u + 0x7fffu + ((u >> 16) & 1u)) >> 16);
}
__device__ __forceinline__ u16 bfbits(float f) {
  union {
    __bf16 b;
    u16 u;
  } c;
  c.b = (__bf16)f;  // native V_CVT (RNE)
  return c.u;
}

__device__ __forceinline__ f32x4 mfma16(b16x8 a, b16x8 b, f32x4 c) {
  return __builtin_amdgcn_mfma_f32_16x16x32_bf16(a, b, c, 0, 0, 0);
}

// async global->LDS, 16B per lane. LDS dest = wave-uniform base + lane*16.
__device__ __forceinline__ void cp16(const u16* g, u16* l) {
  __builtin_amdgcn_global_load_lds(
      (const __attribute__((address_space(1))) u32*)(g),
      (__attribute__((address_space(3))) u32*)(l), 16, 0, 0);
}

// ---------------------------------------------------------------------------
// Weight convert+transpose: WT[n][k] = bf16(W[k][n]), W f32 1024x1024.
// wtq/wtk/wtv land contiguous in ws -> fused B matrix [3072][1024] for QKV.
// ---------------------------------------------------------------------------
__global__ __launch_bounds__(1024) void wconv_kernel(
    const float* __restrict__ w0, const float* __restrict__ w1,
    const float* __restrict__ w2, const float* __restrict__ w3,
    u16* __restrict__ t0, u16* __restrict__ t1, u16* __restrict__ t2,
    u16* __restrict__ t3) {
  __shared__ float tile[32][33];
  const int z = blockIdx.z;
  const float* src = (z == 0) ? w0 : (z == 1) ? w1 : (z == 2) ? w2 : w3;
  u16* dst = (z == 0) ? t0 : (z == 1) ? t1 : (z == 2) ? t2 : t3;
  const int tx = threadIdx.x, ty = threadIdx.y;
  const int x0 = blockIdx.x * 32, y0 = blockIdx.y * 32;
  tile[ty][tx] = src[(size_t)(y0 + ty) * D_ + x0 + tx];
  __syncthreads();
  dst[(size_t)(x0 + ty) * D_ + y0 + tx] = f2bf(tile[tx][ty]);
}

// ---------------------------------------------------------------------------
// x convert: f32 -> bf16, 8M elements, 4/thread
// ---------------------------------------------------------------------------
__global__ __launch_bounds__(256) void xconv_kernel(const float* __restrict__ x,
                                                    u16* __restrict__ xb) {
  const size_t i = ((size_t)blockIdx.x * 256 + threadIdx.x) * 4;
  const float4 v = *(const float4*)(x + i);
  u16 o[4] = {f2bf(v.x), f2bf(v.y), f2bf(v.z), f2bf(v.w)};
  uint2 pack;
  pack.x = ((u32)o[1] << 16) | o[0];
  pack.y = ((u32)o[3] << 16) | o[2];
  *(uint2*)(xb + i) = pack;
}

// ---------------------------------------------------------------------------
// 128x128 GEMM mainloop, BK=64, 256 threads (4 waves, 2Mx2N, wave 64x64),
// double-buffered LDS 2x32KB = 64KB -> 2 blocks/CU (verified round 12).
// ---------------------------------------------------------------------------
#define BUF128_ 16384  // u16 per buffer: A 128x64 (8192) + B 128x64 (8192)

__device__ __forceinline__ void gemm128_mainloop(
    const u16* __restrict__ A, const u16* __restrict__ BT, int K, int m0,
    int n0, u16* lds, f32x4 (&acc)[4][4]) {
  const int t = threadIdx.x;
  const int lane = t & 63;
  const int l15 = lane & 15;
  const int q4 = lane >> 4;
  const int w = t >> 6;            // 0..3
  const int mwave = (w >> 1) * 64; // 2M x 2N wave grid, 64x64 each
  const int nwave = (w & 1) * 64;

  const f32x4 zero = {0.f, 0.f, 0.f, 0.f};
#pragma unroll
  for (int mt = 0; mt < 4; ++mt)
#pragma unroll
    for (int nt = 0; nt < 4; ++nt) acc[mt][nt] = zero;

  const int rbase = t >> 3;                      // 0..31
  const int scol = ((t & 7) ^ (rbase & 7)) * 8;  // pre-swizzled global col
  const u16* Ag = A + (size_t)(m0 + rbase) * K + scol;
  const u16* Bg = BT + (size_t)(n0 + rbase) * K + scol;
  const int sx = l15 & 7;

  // one stage = 8 cp16/thread (4x A 32-row pieces + 4x B)
  auto STAGE = [&](int kt, int bufi) {
    u16* Ab = lds + bufi * BUF128_;
    u16* Bb = Ab + 8192;
    const int k0 = kt * 64;
#pragma unroll
    for (int c = 0; c < 4; ++c)
      cp16(Ag + (size_t)(c * 32) * K + k0, Ab + c * 2048 + t * 8);
#pragma unroll
    for (int c = 0; c < 4; ++c)
      cp16(Bg + (size_t)(c * 32) * K + k0, Bb + c * 2048 + t * 8);
  };

  const int NT = K / 64;  // 16
  STAGE(0, 0);

  int cur = 0;
  for (int kt = 0; kt < NT; ++kt) {
    if (kt + 1 < NT) STAGE(kt + 1, cur ^ 1);  // issue BEFORE the wait
    // readiness of buf[cur]: retire only the oldest 8 (counted vmcnt)
    if (kt + 1 < NT)
      asm volatile("s_waitcnt vmcnt(8)" ::: "memory");
    else
      asm volatile("s_waitcnt vmcnt(0)" ::: "memory");
    asm volatile("s_barrier" ::: "memory");

    const u16* Ab = lds + cur * BUF128_;
    const u16* Bb = Ab + 8192;

    // all 16 fragment reads for both kk halves, back-to-back (kk0 first)
    b16x8 af[4][2], bf2[4][2];
#pragma unroll
    for (int kk = 0; kk < 2; ++kk) {
      const int cc = ((kk * 4 + q4) ^ sx) * 8;
#pragma unroll
      for (int mt = 0; mt < 4; ++mt)
        af[mt][kk] = *(const b16x8*)(Ab + (mwave + mt * 16 + l15) * 64 + cc);
#pragma unroll
      for (int nt = 0; nt < 4; ++nt)
        bf2[nt][kk] = *(const b16x8*)(Bb + (nwave + nt * 16 + l15) * 64 + cc);
    }
    __builtin_amdgcn_sched_barrier(0);

    // kk0 MFMA (compiler inserts counted lgkm waits)
    __builtin_amdgcn_s_setprio(1);
#pragma unroll
    for (int mt = 0; mt < 4; ++mt)
#pragma unroll
      for (int nt = 0; nt < 4; ++nt)
        acc[mt][nt] = mfma16(af[mt][0], bf2[nt][0], acc[mt][nt]);
    __builtin_amdgcn_s_setprio(0);

    // all waves' reads of buf[cur] complete before anyone can restage it
    asm volatile("s_waitcnt lgkmcnt(0)" ::: "memory");
    asm volatile("s_barrier" ::: "memory");

    __builtin_amdgcn_s_setprio(1);
#pragma unroll
    for (int mt = 0; mt < 4; ++mt)
#pragma unroll
      for (int nt = 0; nt < 4; ++nt)
        acc[mt][nt] = mfma16(af[mt][1], bf2[nt][1], acc[mt][nt]);
    __builtin_amdgcn_s_setprio(0);

    cur ^= 1;
  }
}

// ---------------------------------------------------------------------------
// Fused QKV projection (128x128 tiles, verified round 12): grid 1536 =
// 64by x 24bx, 2 blocks/CU -> 3 rounds. XCD x owns by {8x..8x+7}.
// z=0 -> Q [B,H,S,HD], z=1 -> K [B,H,S,HD], z=2 -> V^T [B,H,HD,S]
// ---------------------------------------------------------------------------
__global__ __launch_bounds__(256, 2) void qkv_gemm_kernel(
    const u16* __restrict__ xb, const u16* __restrict__ wt3,
    const float* __restrict__ bq, const float* __restrict__ bk,
    const float* __restrict__ bv, u16* __restrict__ Q, u16* __restrict__ Kb,
    u16* __restrict__ VT) {
  __shared__ __align__(16) u16 lds[2 * BUF128_];  // 64 KB
  const int wg = blockIdx.x;
  const int xcd = wg & 7;
  const int s = wg >> 3;             // 0..191
  const int by = xcd * 8 + (s & 7);  // 0..63: 8 A-panels pinned per XCD
  const int bx = s >> 3;             // 0..23: B streams
  const int m0 = by * 128;
  const int n0 = bx * 128;  // fused col base 0..2944

  f32x4 acc[4][4];
  gemm128_mainloop(xb, wt3, D_, m0, n0, lds, acc);

  const int t = threadIdx.x;
  const int lane = t & 63, w = t >> 6;
  const int l15 = lane & 15, q4 = lane >> 4;
  const int mwave = (w >> 1) * 64, nwave = (w & 1) * 64;

  const int z = n0 >> 10;  // uniform per block
  u16* out = (z == 0) ? Q : (z == 1) ? Kb : VT;
  const float* bias = (z == 0) ? bq : (z == 1) ? bk : bv;

  for (int nt = 0; nt < 4; ++nt) {
    const int nf = n0 + nwave + nt * 16 + l15;  // fused col
    const int n1 = nf & 1023;                   // col within matrix
    const float bias_v = bias[n1];
    const int h = n1 >> 6, hd = n1 & 63;
    for (int mt = 0; mt < 4; ++mt) {
      for (int r = 0; r < 4; ++r) {
        const int m = m0 + mwave + mt * 16 + q4 * 4 + r;
        const int b = m >> 10, ss = m & 1023;
        const float v = acc[mt][nt][r] + bias_v;
        size_t idx;
        if (z < 2)
          idx = (((size_t)(b * H_ + h)) * S_ + ss) * HD_ + hd;
        else
          idx = (((size_t)(b * H_ + h)) * HD_ + hd) * S_ + ss;
        out[idx] = f2bf(v);
      }
    }
  }
}

// ---------------------------------------------------------------------------
// 256x128 GEMM mainloop (round-11 verified config, 4Mx2N wave 64x64) --
// used by out_gemm (grid 256 = 1 block/CU, one round).
// ---------------------------------------------------------------------------
#define ABUF_ 16384  // u16: 256x64 A tile
#define BBUF_ 8192   // u16: 128x64 B tile
#define BUFSZ_ (ABUF_ + BBUF_)

__device__ __forceinline__ void gemm256x128_mainloop(
    const u16* __restrict__ A, const u16* __restrict__ BT, int K, int m0,
    int n0, u16* lds, f32x4 (&acc)[4][4]) {
  const int t = threadIdx.x;
  const int lane = t & 63;
  const int l15 = lane & 15;
  const int q4 = lane >> 4;
  const int w = t >> 6;
  const int wm = w >> 1;  // 0..3 -> 64-row slice
  const int wn = w & 1;   // 0..1 -> 64-col slice

  const f32x4 zero = {0.f, 0.f, 0.f, 0.f};
#pragma unroll
  for (int mt = 0; mt < 4; ++mt)
#pragma unroll
    for (int nt = 0; nt < 4; ++nt) acc[mt][nt] = zero;

  const int rbase = t >> 3;                      // 0..63
  const int scol = ((t & 7) ^ (rbase & 7)) * 8;  // pre-swizzled global col
  const u16* Ag = A + (size_t)(m0 + rbase) * K + scol;
  const u16* Bg = BT + (size_t)(n0 + rbase) * K + scol;
  const int sx = l15 & 7;

  auto STAGE = [&](int kt, int bufi) {
    u16* Ab = lds + bufi * BUFSZ_;
    u16* Bb = Ab + ABUF_;
    const int k0 = kt * 64;
#pragma unroll
    for (int c = 0; c < 4; ++c)
      cp16(Ag + (size_t)(c * 64) * K + k0, Ab + c * 4096 + t * 8);
#pragma unroll
    for (int c = 0; c < 2; ++c)
      cp16(Bg + (size_t)(c * 64) * K + k0, Bb + c * 4096 + t * 8);
  };

  const int NT = K / 64;  // 16
  STAGE(0, 0);
  STAGE(1, 1);

  int cur = 0;
  for (int kt = 0; kt < NT; ++kt) {
    if (kt + 2 < NT) {
      int nb = cur + 2;
      if (nb >= 3) nb -= 3;
      STAGE(kt + 2, nb);
    }
    if (kt + 2 < NT)
      asm volatile("s_waitcnt vmcnt(12)" ::: "memory");
    else if (kt + 1 < NT)
      asm volatile("s_waitcnt vmcnt(6)" ::: "memory");
    else
      asm volatile("s_waitcnt vmcnt(0)" ::: "memory");
    asm volatile("s_barrier" ::: "memory");

    const u16* Ab = lds + cur * BUFSZ_;
    const u16* Bb = Ab + ABUF_;

    b16x8 af[4][2], bf2[4][2];
#pragma unroll
    for (int kk = 0; kk < 2; ++kk) {
      const int cc = ((kk * 4 + q4) ^ sx) * 8;
#pragma unroll
      for (int mt = 0; mt < 4; ++mt)
        af[mt][kk] = *(const b16x8*)(Ab + (wm * 64 + mt * 16 + l15) * 64 + cc);
#pragma unroll
      for (int nt = 0; nt < 4; ++nt)
        bf2[nt][kk] = *(const b16x8*)(Bb + (wn * 64 + nt * 16 + l15) * 64 + cc);
    }
    __builtin_amdgcn_sched_barrier(0);

    __builtin_amdgcn_s_setprio(1);
#pragma unroll
    for (int mt = 0; mt < 4; ++mt)
#pragma unroll
      for (int nt = 0; nt < 4; ++nt)
        acc[mt][nt] = mfma16(af[mt][0], bf2[nt][0], acc[mt][nt]);
    __builtin_amdgcn_s_setprio(0);

    asm volatile("s_waitcnt lgkmcnt(0)" ::: "memory");
    asm volatile("s_barrier" ::: "memory");

    __builtin_amdgcn_s_setprio(1);
#pragma unroll
    for (int mt = 0; mt < 4; ++mt)
#pragma unroll
      for (int nt = 0; nt < 4; ++nt)
        acc[mt][nt] = mfma16(af[mt][1], bf2[nt][1], acc[mt][nt]);
    __builtin_amdgcn_s_setprio(0);

    ++cur;
    if (cur == 3) cur = 0;
  }
}

// ---------------------------------------------------------------------------
// Flash attention, fixed-max softmax, transposed-score formulation.
// QBLK=128, KVBLK=128 (verified round 13).
// ROUND-14 CHANGE (single edit): VPAD_ 136 -> 132. 136u16 = 68 dwords === 4
// (mod 32) put V writes AND reads in the 8-way bank class (start = 4*(r+c)
// mod 32 -> (r+c) mod 8, 8 lanes/group) -- measured conflicts 3.2M -> 7.4M.
// 132u16 = 66 dwords === 2 (mod 32) restores the proven PAD_=68 class
// (start = 2r+4c -> ~2-way writes, 4-way reads). 8B-aligned rows, same as
// PAD_=68 used in every passing round.
// ---------------------------------------------------------------------------
#define PAD_ 68    // K row stride (verified conflict-class: 34 dw === 2 mod 32)
#define VPAD_ 132  // V row stride: 66 dw === 2 mod 32 (same class as PAD_)
#define QPAD_ 72   // Q/P row stride (144B)
__global__ __launch_bounds__(512) void attn_kernel(
    const u16* __restrict__ Q, const u16* __restrict__ Kb,
    const u16* __restrict__ VT, const int* __restrict__ mask,
    u16* __restrict__ ctx) {
  __shared__ __align__(16) u16 QPlds[128 * QPAD_];  // 18432 B
  __shared__ __align__(16) u16 Klds[128 * PAD_];    // 17408 B: [key128][d64]
  __shared__ __align__(16) u16 Vlds[64 * VPAD_];    // 16896 B: [d64][key128]
  __shared__ __align__(16) float Mlds[1024];        // 4096 B

  const int t = threadIdx.x;
  const int lane = t & 63, w = t >> 6;  // w 0..7
  const int l15 = lane & 15, q4 = lane >> 4;
  const int id = blockIdx.x;
  const int bh = id & 127;  // XCD = id%8 = bh%8 -> q-tiles of a bh co-locate
  const int b = bh >> 4, h = bh & 15;
  const int q0 = (id >> 7) * 128;  // 8 q-tiles of 128 rows

  const u16* Qbh = Q + (size_t)bh * S_ * HD_;
  const u16* Kbh = Kb + (size_t)bh * S_ * HD_;
  const u16* Vbh = VT + (size_t)bh * S_ * HD_;  // [HD][S]
  const int* maskb = mask + b * S_;

  const int srow = t >> 3, scol = (t & 7) * 8;  // srow 0..63
  {  // stage Q tile [128][64] + mask into LDS
    b16x8 q0v = *(const b16x8*)(Qbh + (size_t)(q0 + srow) * HD_ + scol);
    b16x8 q1v = *(const b16x8*)(Qbh + (size_t)(q0 + srow + 64) * HD_ + scol);
    const int2 mv = *(const int2*)(maskb + t * 2);
    *(b16x8*)(QPlds + srow * QPAD_ + scol) = q0v;
    *(b16x8*)(QPlds + (srow + 64) * QPAD_ + scol) = q1v;
    float2 mf;
    mf.x = -14427.0f * (float)mv.x;
    mf.y = -14427.0f * (float)mv.y;
    *(float2*)(Mlds + t * 2) = mf;
  }
  __syncthreads();
  // Q B-frags (lane holds Q[q=l15][d=q4*8+j]), wave-private rows
  b16x8 aq[2];
  aq[0] = *(const b16x8*)(QPlds + (w * 16 + l15) * QPAD_ + q4 * 8);
  aq[1] = *(const b16x8*)(QPlds + (w * 16 + l15) * QPAD_ + 32 + q4 * 8);

  const f32x4 zero = {0.f, 0.f, 0.f, 0.f};
  f32x4 acc[4];  // O^T tiles: acc[nt] row d=nt*16+q4*4+r, col q=l15
  for (int nt = 0; nt < 4; ++nt) acc[nt] = zero;
  float lsum = 0.f;                  // partial row-sum for q=l15
  u16* Pw = QPlds + w * 16 * QPAD_;  // wave-private P: [q(16)][key(64)]
  const float c1 = 0.18033688f;      // 0.125 * log2(e)

  // prologue prefetch for j=0: K keys 0..127 (2 rows/thread), V d-row srow
  // cols 0..63 and 64..127
  b16x8 kv0 = *(const b16x8*)(Kbh + (size_t)srow * HD_ + scol);
  b16x8 kv1 = *(const b16x8*)(Kbh + (size_t)(srow + 64) * HD_ + scol);
  b16x8 vv0 = *(const b16x8*)(Vbh + (size_t)srow * S_ + scol);
  b16x8 vv1 = *(const b16x8*)(Vbh + (size_t)srow * S_ + 64 + scol);

  for (int j = 0; j < 8; ++j) {
    const int key0 = j * 128;
    __syncthreads();  // (A) prior iteration's K/V LDS reads complete
    *(b16x8*)(Klds + srow * PAD_ + scol) = kv0;
    *(b16x8*)(Klds + (srow + 64) * PAD_ + scol) = kv1;
    *(b16x8*)(Vlds + srow * VPAD_ + scol) = vv0;
    *(b16x8*)(Vlds + srow * VPAD_ + 64 + scol) = vv1;
    __syncthreads();  // (B) staging visible

    if (j < 7) {  // prefetch next tile's K/V during compute
      const int kn = key0 + 128;
      kv0 = *(const b16x8*)(Kbh + (size_t)(kn + srow) * HD_ + scol);
      kv1 = *(const b16x8*)(Kbh + (size_t)(kn + srow + 64) * HD_ + scol);
      vv0 = *(const b16x8*)(Vbh + (size_t)srow * S_ + kn + scol);
      vv1 = *(const b16x8*)(Vbh + (size_t)srow * S_ + kn + 64 + scol);
    }

#pragma unroll
    for (int ks = 0; ks < 2; ++ks) {  // two 64-key sub-rounds, no barriers
      // S^T = K·Q^T: sf[nt] rows key=ks*64+nt*16+q4*4+r, col q=l15
      f32x4 sf[4];
      for (int nt = 0; nt < 4; ++nt) sf[nt] = zero;
      for (int kk = 0; kk < 2; ++kk)
        for (int nt = 0; nt < 4; ++nt) {
          b16x8 bk = *(const b16x8*)(Klds + (ks * 64 + nt * 16 + l15) * PAD_ +
                                     kk * 32 + q4 * 8);
          sf[nt] = mfma16(bk, aq[kk], sf[nt]);
        }

      // fixed-max softmax; mask indexed by key (row) -> broadcast float4
      for (int nt = 0; nt < 4; ++nt) {
        const float4 mk =
            *(const float4*)(Mlds + key0 + ks * 64 + nt * 16 + q4 * 4);
        float p0 = __builtin_amdgcn_exp2f(sf[nt][0] * c1 + mk.x);
        float p1 = __builtin_amdgcn_exp2f(sf[nt][1] * c1 + mk.y);
        float p2 = __builtin_amdgcn_exp2f(sf[nt][2] * c1 + mk.z);
        float p3 = __builtin_amdgcn_exp2f(sf[nt][3] * c1 + mk.w);
        lsum += (p0 + p1) + (p2 + p3);
        uint2 pk;
        pk.x = ((u32)bfbits(p1) << 16) | bfbits(p0);
        pk.y = ((u32)bfbits(p3) << 16) | bfbits(p2);
        // P[q=l15][key=nt*16+q4*4 .. +3]: one b64 write
        *(uint2*)(Pw + l15 * QPAD_ + nt * 16 + q4 * 4) = pk;
      }
      // wave-private handoff: drain the 4 P writes only
      asm volatile("s_waitcnt lgkmcnt(0)" ::: "memory");

      // O^T += V^T·P: A=V-frag (col ks*64+..), B=P-frag (b128 row read)
      for (int kk = 0; kk < 2; ++kk) {
        b16x8 bp = *(const b16x8*)(Pw + l15 * QPAD_ + kk * 32 + q4 * 8);
        for (int nt = 0; nt < 4; ++nt) {
          b16x8 vb = *(const b16x8*)(Vlds + (nt * 16 + l15) * VPAD_ + ks * 64 +
                                     kk * 32 + q4 * 8);
          acc[nt] = mfma16(vb, bp, acc[nt]);
        }
      }
    }
  }

  // row-sum: quads hold disjoint key quarters -> reduce across quads
  lsum += __shfl_xor(lsum, 16);
  lsum += __shfl_xor(lsum, 32);
  const float inv = 1.0f / lsum;

  // epilogue: lane writes 4 consecutive d at fixed row s -> dwordx2 stores
  const int srw = q0 + w * 16 + l15;
  u16* crow = ctx + ((size_t)(b * S_ + srw)) * D_ + h * 64;
  for (int nt = 0; nt < 4; ++nt) {
    uint2 pk;
    pk.x = ((u32)bfbits(acc[nt][1] * inv) << 16) | bfbits(acc[nt][0] * inv);
    pk.y = ((u32)bfbits(acc[nt][3] * inv) << 16) | bfbits(acc[nt][2] * inv);
    *(uint2*)(crow + nt * 16 + q4 * 4) = pk;
  }
}

// ---------------------------------------------------------------------------
// Output projection + bias + residual(x f32) -> y (fp32).
// Round-11 verified config: 256x128 tiles, grid 256 = 32by x 8bx = 1
// block/CU, one round. XCD x owns by {4x..4x+3} (A 2MB) + wto (2MB).
// ---------------------------------------------------------------------------
__global__ __launch_bounds__(512, 2) void out_gemm_kernel(
    const u16* __restrict__ ctx, const u16* __restrict__ wto,
    const float* __restrict__ bo, const float* __restrict__ x,
    float* __restrict__ y) {
  __shared__ __align__(16) u16 lds[3 * BUFSZ_];  // 144 KB
  const int wg = blockIdx.x;
  const int xcd = wg & 7;
  const int s = wg >> 3;             // 0..31
  const int by = xcd * 4 + (s & 3);  // 0..31
  const int bx = s >> 2;             // 0..7
  const int m0 = by * 256, n0 = bx * 128;

  f32x4 acc[4][4];
  gemm256x128_mainloop(ctx, wto, D_, m0, n0, lds, acc);

  const int t = threadIdx.x;
  const int lane = t & 63, w = t >> 6;
  const int l15 = lane & 15, q4 = lane >> 4;
  const int wm = w >> 1, wn = w & 1;

  for (int nt = 0; nt < 4; ++nt) {
    const int n = n0 + wn * 64 + nt * 16 + l15;
    const float bias = bo[n];
    for (int mt = 0; mt < 4; ++mt) {
      for (int r = 0; r < 4; ++r) {
        const int m = m0 + wm * 64 + mt * 16 + q4 * 4 + r;
        y[(size_t)m * D_ + n] = acc[mt][nt][r] + bias + x[(size_t)m * D_ + n];
      }
    }
  }
}

// ---------------------------------------------------------------------------
// Row LayerNorm: one block per row of 1024, f32 in, f32 out
// ---------------------------------------------------------------------------
__global__ __launch_bounds__(256) void ln_kernel(const float* __restrict__ y,
                                                 const float* __restrict__ g,
                                                 const float* __restrict__ be,
                                                 float* __restrict__ out) {
  const int row = blockIdx.x, t = threadIdx.x;
  const float* yr = y + (size_t)row * D_;
  const float4 v = *(const float4*)(yr + t * 4);
  float s = v.x + v.y + v.z + v.w;
  float ss = v.x * v.x + v.y * v.y + v.z * v.z + v.w * v.w;
  for (int off = 1; off < 64; off <<= 1) {
    s += __shfl_xor(s, off);
    ss += __shfl_xor(ss, off);
  }
  __shared__ float red[8];
  const int w = t >> 6, lane = t & 63;
  if (lane == 0) {
    red[w] = s;
    red[4 + w] = ss;
  }
  __syncthreads();
  s = red[0] + red[1] + red[2] + red[3];
  ss = red[4] + red[5] + red[6] + red[7];
  const float mu = s * (1.f / 1024.f);
  const float var = ss * (1.f / 1024.f) - mu * mu;
  const float rs = rsqrtf(var + 1e-6f);
  const int c = t * 4;
  const float4 gv = *(const float4*)(g + c);
  const float4 bv = *(const float4*)(be + c);
  float4 o;
  o.x = (v.x - mu) * rs * gv.x + bv.x;
  o.y = (v.y - mu) * rs * gv.y + bv.y;
  o.z = (v.z - mu) * rs * gv.z + bv.z;
  o.w = (v.w - mu) * rs * gv.w + bv.w;
  *(float4*)(out + (size_t)row * D_ + c) = o;
}

// ---------------------------------------------------------------------------
extern "C" void kernel_launch(void* const* d_in, const int* in_sizes, int n_in,
                              void* d_out, int out_size, void* d_ws,
                              size_t ws_size, hipStream_t stream) {
  const float* x = (const float*)d_in[0];
  const int* mask = (const int*)d_in[1];
  const float* wq = (const float*)d_in[2];
  const float* bq = (const float*)d_in[3];
  const float* wk = (const float*)d_in[4];
  const float* bk = (const float*)d_in[5];
  const float* wv = (const float*)d_in[6];
  const float* bv = (const float*)d_in[7];
  const float* wo = (const float*)d_in[8];
  const float* bo = (const float*)d_in[9];
  const float* gamma = (const float*)d_in[10];
  const float* beta = (const float*)d_in[11];
  float* out = (float*)d_out;

  char* ws = (char*)d_ws;
  const size_t MB = 1024ull * 1024ull;
  u16* wtq = (u16*)(ws + 0 * MB);  // wtq/wtk/wtv contiguous = fused [3072][1024]
  u16* wtk = (u16*)(ws + 2 * MB);
  u16* wtv = (u16*)(ws + 4 * MB);
  u16* wto = (u16*)(ws + 6 * MB);
  u16* xb = (u16*)(ws + 8 * MB);    // 16MB bf16 x; dead after qkv_gemm
  u16* ctx = (u16*)(ws + 8 * MB);   // aliases xb (written by attn)
  u16* Qb = (u16*)(ws + 24 * MB);   // 16MB; dead after attn
  u16* Kb = (u16*)(ws + 40 * MB);   // 16MB; dead after attn
  u16* VTb = (u16*)(ws + 56 * MB);  // 16MB
  float* y = (float*)(ws + 24 * MB);  // 32MB fp32, aliases Qb+Kb
  // total: 72MB

  wconv_kernel<<<dim3(32, 32, 4), dim3(32, 32), 0, stream>>>(
      wq, wk, wv, wo, wtq, wtk, wtv, wto);
  xconv_kernel<<<8192, 256, 0, stream>>>(x, xb);
  qkv_gemm_kernel<<<1536, 256, 0, stream>>>(xb, wtq, bq, bk, bv, Qb, Kb, VTb);
  attn_kernel<<<1024, 512, 0, stream>>>(Qb, Kb, VTb, mask, ctx);
  out_gemm_kernel<<<256, 512, 0, stream>>>(ctx, wto, bo, x, y);
  ln_kernel<<<8192, 256, 0, stream>>>(y, gamma, beta, out);
}